// Round 1
// baseline (567.013 us; speedup 1.0000x reference)
//
#include <hip/hip_runtime.h>
#include <cstdint>
#include <cstddef>

// ---------------- types / helpers ----------------
typedef _Float16 f16x8 __attribute__((ext_vector_type(8)));
typedef _Float16 f16x4 __attribute__((ext_vector_type(4)));
typedef float    f32x4 __attribute__((ext_vector_type(4)));

#define AS_GLOBAL __attribute__((address_space(1)))
#define AS_LDS    __attribute__((address_space(3)))

__device__ __forceinline__ void load16_to_lds(const _Float16* g, _Float16* l) {
    // async global->LDS, 16 bytes/lane, dest = wave-uniform base + lane*16
    __builtin_amdgcn_global_load_lds((const AS_GLOBAL void*)g, (AS_LDS void*)l, 16, 0, 0);
}

__device__ __forceinline__ float qmax16(float v) {
#pragma unroll
    for (int off = 1; off < 16; off <<= 1) v = fmaxf(v, __shfl_xor(v, off));
    return v;
}
__device__ __forceinline__ float qsum16(float v) {
#pragma unroll
    for (int off = 1; off < 16; off <<= 1) v += __shfl_xor(v, off);
    return v;
}

// ---------------- problem constants ----------------
#define BB   2
#define TT   4096
#define DD   768
#define NH   12
#define HDIM 64
#define D3   2304
#define SCALE 0.125f

// ---------------- cast fp32 -> fp16 ----------------
__global__ void cast_f32_f16(const float* __restrict__ in, _Float16* __restrict__ out, int n) {
    int i = (blockIdx.x * blockDim.x + threadIdx.x) * 4;
    if (i + 3 < n) {
        float4 v = *(const float4*)(in + i);
        f16x4 h;
        h[0] = (_Float16)v.x; h[1] = (_Float16)v.y;
        h[2] = (_Float16)v.z; h[3] = (_Float16)v.w;
        *(f16x4*)(out + i) = h;
    } else {
        for (int j = i; j < n; ++j) out[j] = (_Float16)in[j];
    }
}

// ---------------- transpose + cast: in[R][C] fp32 -> out[C][R] fp16 ----------------
__global__ void transpose_cast(const float* __restrict__ in, _Float16* __restrict__ out,
                               int R, int C) {
    __shared__ float tile[32][33];
    const int bx = blockIdx.x * 32, by = blockIdx.y * 32;
    const int tx = threadIdx.x, ty = threadIdx.y;   // 32 x 8
#pragma unroll
    for (int j = 0; j < 32; j += 8)
        if (by + ty + j < R && bx + tx < C)
            tile[ty + j][tx] = in[(size_t)(by + ty + j) * C + bx + tx];
    __syncthreads();
#pragma unroll
    for (int j = 0; j < 32; j += 8)
        if (bx + ty + j < C && by + tx < R)
            out[(size_t)(bx + ty + j) * R + by + tx] = (_Float16)tile[tx][ty + j];
}

// ---------------- GEMM: C[M][N] = A[M][K] * Bt[N][K]^T + bias ----------------
// 128x128 tile, BK=32, 256 threads = 4 waves, each wave 64x64.
// M,N multiples of 128; K multiple of 32 (exact fit here, no bounds checks).
template <typename OutT>
__global__ __launch_bounds__(256) void gemm_bt(const _Float16* __restrict__ A,
                                               const _Float16* __restrict__ Bt,
                                               const float* __restrict__ bias,
                                               OutT* __restrict__ C,
                                               int M, int N, int K) {
    __shared__ __align__(16) _Float16 As[128 * 32];
    __shared__ __align__(16) _Float16 Bs[128 * 32];
    const int tid  = threadIdx.x;
    const int wave = tid >> 6, lane = tid & 63, quad = lane >> 4, l16 = lane & 15;
    const int m0 = blockIdx.y * 128, n0 = blockIdx.x * 128;
    const int wm = (wave & 1) * 64, wn = (wave >> 1) * 64;
    const int rowc = lane >> 2, part = lane & 3;   // staging: 16 rows/chunk, 4 lanes/row

    f32x4 acc[4][4];
#pragma unroll
    for (int i = 0; i < 4; ++i)
#pragma unroll
        for (int n = 0; n < 4; ++n) acc[i][n] = f32x4{0.f, 0.f, 0.f, 0.f};

    for (int k0 = 0; k0 < K; k0 += 32) {
        __syncthreads();
#pragma unroll
        for (int cc = 0; cc < 2; ++cc) {
            const int ch = wave * 2 + cc;          // chunk 0..7, 16 rows each
            load16_to_lds(A  + (size_t)(m0 + ch * 16 + rowc) * K + k0 + part * 8,
                          As + ch * 512);
            load16_to_lds(Bt + (size_t)(n0 + ch * 16 + rowc) * K + k0 + part * 8,
                          Bs + ch * 512);
        }
        __syncthreads();
#pragma unroll
        for (int i = 0; i < 4; ++i) {
            f16x8 a = *(const f16x8*)(As + (wm + i * 16 + l16) * 32 + quad * 8);
#pragma unroll
            for (int n = 0; n < 4; ++n) {
                f16x8 b = *(const f16x8*)(Bs + (wn + n * 16 + l16) * 32 + quad * 8);
                acc[i][n] = __builtin_amdgcn_mfma_f32_16x16x32_f16(a, b, acc[i][n], 0, 0, 0);
            }
        }
    }
    // epilogue: D row = quad*4+reg, col = l16 (verified C/D layout)
#pragma unroll
    for (int i = 0; i < 4; ++i)
#pragma unroll
        for (int n = 0; n < 4; ++n)
#pragma unroll
            for (int r = 0; r < 4; ++r) {
                const int row = m0 + wm + i * 16 + quad * 4 + r;
                const int col = n0 + wn + n * 16 + l16;
                C[(size_t)row * N + col] = (OutT)(acc[i][n][r] + bias[col]);
            }
}

// ---------------- flash attention ----------------
// grid (T/64, H, B), 256 threads = 4 waves; wave handles 16 query rows.
// qkv: fp16 [B*T][2304] (Q|K|V interleaved per row), ao: fp16 [B*T][768]
__global__ __launch_bounds__(256) void attn_kernel(const _Float16* __restrict__ qkv,
                                                   _Float16* __restrict__ ao) {
    __shared__ __align__(16) _Float16 Ks[64][72];      // [key][hd], pad 72 -> 2-way banks
    __shared__ __align__(16) _Float16 Vt[64][72];      // [hd][key]
    __shared__ __align__(16) _Float16 Ps[4][16][72];   // per-wave P round-trip
    const int b = blockIdx.z, h = blockIdx.y;
    const int q0 = blockIdx.x * 64;
    const int tid = threadIdx.x;
    const int wave = tid >> 6, lane = tid & 63, quad = lane >> 4, l16 = lane & 15;

    // Q fragments (A-operand layout: m=l16, k=quad*8+j), straight from global
    f16x8 aq[2];
    {
        const int q = q0 + wave * 16 + l16;
        const _Float16* qp = qkv + (size_t)(b * TT + q) * D3 + h * HDIM + quad * 8;
        aq[0] = *(const f16x8*)qp;
        aq[1] = *(const f16x8*)(qp + 32);
    }

    f32x4 o[4];
    float mrow[4], lrow[4];
#pragma unroll
    for (int n = 0; n < 4; ++n) o[n] = f32x4{0.f, 0.f, 0.f, 0.f};
#pragma unroll
    for (int r = 0; r < 4; ++r) { mrow[r] = -1e30f; lrow[r] = 0.f; }

    const int nkt = q0 / 64 + 1;   // causal: only key tiles with k0 <= q0
    for (int kt = 0; kt < nkt; ++kt) {
        const int k0 = kt * 64;
        __syncthreads();           // all waves done with previous Ks/Vt
        // ---- stage K (straight) and V (transposed), 512 16B-tasks / 256 thr ----
#pragma unroll
        for (int p = 0; p < 2; ++p) {
            const int task = tid + p * 256;
            const int key = task >> 3, c = task & 7;
            const _Float16* kp =
                qkv + (size_t)(b * TT + k0 + key) * D3 + DD + h * HDIM + c * 8;
            f16x8 kv = *(const f16x8*)kp;
            *(f16x8*)&Ks[key][c * 8] = kv;
            f16x8 vv = *(const f16x8*)(kp + DD);
#pragma unroll
            for (int j = 0; j < 8; ++j) Vt[c * 8 + j][key] = vv[j];
        }
        __syncthreads();

        // ---- S = Q K^T (16 q x 64 keys per wave) ----
        f32x4 s[4];
#pragma unroll
        for (int n = 0; n < 4; ++n) s[n] = f32x4{0.f, 0.f, 0.f, 0.f};
#pragma unroll
        for (int n = 0; n < 4; ++n)
#pragma unroll
            for (int kh = 0; kh < 2; ++kh) {
                f16x8 bk = *(const f16x8*)&Ks[n * 16 + l16][kh * 32 + quad * 8];
                s[n] = __builtin_amdgcn_mfma_f32_16x16x32_f16(aq[kh], bk, s[n], 0, 0, 0);
            }

        // ---- scale + causal mask ----
        float sv[4][4];
        const bool need_mask = (k0 + 64 > q0);
#pragma unroll
        for (int n = 0; n < 4; ++n) {
            const int kg = k0 + n * 16 + l16;
#pragma unroll
            for (int r = 0; r < 4; ++r) {
                float x = s[n][r] * SCALE;
                if (need_mask) {
                    const int qg = q0 + wave * 16 + quad * 4 + r;
                    if (kg > qg) x = -1e30f;
                }
                sv[n][r] = x;
            }
        }

        // ---- online softmax per row (row = quad*4+r, spread across 16 lanes) ----
#pragma unroll
        for (int r = 0; r < 4; ++r) {
            float tm = fmaxf(fmaxf(sv[0][r], sv[1][r]), fmaxf(sv[2][r], sv[3][r]));
            tm = qmax16(tm);
            const float mn = fmaxf(mrow[r], tm);
            const float al = __expf(mrow[r] - mn);
            mrow[r] = mn;
            float ps = 0.f;
#pragma unroll
            for (int n = 0; n < 4; ++n) {
                const float p = __expf(sv[n][r] - mn);
                sv[n][r] = p;
                ps += p;
            }
            ps = qsum16(ps);
            lrow[r] = lrow[r] * al + ps;
#pragma unroll
            for (int n = 0; n < 4; ++n) o[n][r] *= al;
            // write P row to LDS (C-layout -> A-layout transform)
#pragma unroll
            for (int n = 0; n < 4; ++n)
                Ps[wave][quad * 4 + r][n * 16 + l16] = (_Float16)sv[n][r];
        }

        // ---- O += P V ----
#pragma unroll
        for (int n = 0; n < 4; ++n)
#pragma unroll
            for (int kh = 0; kh < 2; ++kh) {
                f16x8 ap = *(const f16x8*)&Ps[wave][l16][kh * 32 + quad * 8];
                f16x8 bv = *(const f16x8*)&Vt[n * 16 + l16][kh * 32 + quad * 8];
                o[n] = __builtin_amdgcn_mfma_f32_16x16x32_f16(ap, bv, o[n], 0, 0, 0);
            }
    }

    // ---- finalize: divide by l, write [B*T][768] fp16 ----
#pragma unroll
    for (int n = 0; n < 4; ++n)
#pragma unroll
        for (int r = 0; r < 4; ++r) {
            const int q = q0 + wave * 16 + quad * 4 + r;
            const int col = h * HDIM + n * 16 + l16;
            ao[(size_t)(b * TT + q) * DD + col] = (_Float16)(o[n][r] / lrow[r]);
        }
}

// ---------------- launch ----------------
extern "C" void kernel_launch(void* const* d_in, const int* in_sizes, int n_in,
                              void* d_out, int out_size, void* d_ws, size_t ws_size,
                              hipStream_t stream) {
    const float* x     = (const float*)d_in[0];   // [2,4096,768]
    const float* Wqkv  = (const float*)d_in[1];   // [768,2304]
    const float* bqkv  = (const float*)d_in[2];   // [2304]
    const float* Wout  = (const float*)d_in[3];   // [768,768]
    const float* bout  = (const float*)d_in[4];   // [768]
    float* out = (float*)d_out;                   // [2,4096,768]

    char* ws = (char*)d_ws;
    _Float16* Xh    = (_Float16*)ws;  ws += (size_t)BB * TT * DD * 2;        // 12 MB
    _Float16* Wqkvt = (_Float16*)ws;  ws += (size_t)D3 * DD * 2;             // 3.5 MB
    _Float16* Wot   = (_Float16*)ws;  ws += (size_t)DD * DD * 2;             // 1.2 MB
    _Float16* QKVh  = (_Float16*)ws;  ws += (size_t)BB * TT * D3 * 2;        // 37.7 MB
    _Float16* AOh   = (_Float16*)ws;  ws += (size_t)BB * TT * DD * 2;        // 12 MB

    const int M = BB * TT;  // 8192

    cast_f32_f16<<<(M * DD) / (256 * 4), 256, 0, stream>>>(x, Xh, M * DD);
    transpose_cast<<<dim3(D3 / 32, DD / 32), dim3(32, 8), 0, stream>>>(Wqkv, Wqkvt, DD, D3);
    transpose_cast<<<dim3(DD / 32, DD / 32), dim3(32, 8), 0, stream>>>(Wout, Wot, DD, DD);

    gemm_bt<_Float16><<<dim3(D3 / 128, M / 128), 256, 0, stream>>>(
        Xh, Wqkvt, bqkv, QKVh, M, D3, DD);

    attn_kernel<<<dim3(TT / 64, NH, BB), 256, 0, stream>>>(QKVh, AOh);

    gemm_bt<float><<<dim3(DD / 128, M / 128), 256, 0, stream>>>(
        AOh, Wot, bout, out, M, DD, DD);
}